// Round 1
// baseline (1197.893 us; speedup 1.0000x reference)
//
#include <hip/hip_runtime.h>

// CWTConv2D: x (32,512,512) f32 -> round; k (32,3,3) -> round+clip to {-1,0,1},
// spatially flipped conv (VALID) -> out (32,510,510,32) NHWC f32, +round(bias), relu.

#define BATCH 32
#define H 512
#define W 512
#define NF 32
#define HO 510
#define WO 510

__global__ __launch_bounds__(256) void cwt_conv_kernel(
    const float* __restrict__ x,
    const float* __restrict__ kw,
    const float* __restrict__ bias,
    float* __restrict__ out,
    int total4, int nthreads)
{
    int g = blockIdx.x * blockDim.x + threadIdx.x;
    int f4 = g & 7;  // which group of 4 filters; invariant over grid-stride (stride % 8 == 0)

    // Hoist + quantize weights for f = 4*f4 .. 4*f4+3. Tap t=(di*3+dj) uses the
    // spatially flipped weight kw[f][2-di][2-dj] = kw[f*9 + (8 - t)].
    float wq[9][4];
    float bq[4];
#pragma unroll
    for (int c = 0; c < 4; ++c) {
        int f = f4 * 4 + c;
#pragma unroll
        for (int t = 0; t < 9; ++t) {
            float v = rintf(kw[f * 9 + (8 - t)]);
            v = fminf(fmaxf(v, -1.0f), 1.0f);
            wq[t][c] = v;
        }
        bq[c] = rintf(bias[f]);
    }

    for (int idx4 = g; idx4 < total4; idx4 += nthreads) {
        int s  = idx4 >> 3;          // spatial index: (b*HO + i)*WO + j
        int j  = s % WO;
        int t2 = s / WO;
        int i  = t2 % HO;
        int b  = t2 / HO;
        const float* xp = x + ((size_t)(b * H + i) * W + j);

        float acc0 = bq[0], acc1 = bq[1], acc2 = bq[2], acc3 = bq[3];
#pragma unroll
        for (int di = 0; di < 3; ++di) {
#pragma unroll
            for (int dj = 0; dj < 3; ++dj) {
                float xv = rintf(xp[di * W + dj]);
                int t = di * 3 + dj;
                acc0 = fmaf(xv, wq[t][0], acc0);
                acc1 = fmaf(xv, wq[t][1], acc1);
                acc2 = fmaf(xv, wq[t][2], acc2);
                acc3 = fmaf(xv, wq[t][3], acc3);
            }
        }
        float4 r;
        r.x = fmaxf(acc0, 0.0f);
        r.y = fmaxf(acc1, 0.0f);
        r.z = fmaxf(acc2, 0.0f);
        r.w = fmaxf(acc3, 0.0f);
        reinterpret_cast<float4*>(out)[idx4] = r;
    }
}

extern "C" void kernel_launch(void* const* d_in, const int* in_sizes, int n_in,
                              void* d_out, int out_size, void* d_ws, size_t ws_size,
                              hipStream_t stream) {
    const float* x    = (const float*)d_in[0];
    const float* kw   = (const float*)d_in[1];
    const float* bias = (const float*)d_in[2];
    float* out = (float*)d_out;

    constexpr int total4 = BATCH * HO * WO * (NF / 4);  // 66,585,600 float4 stores
    const int block = 256;
    const int grid  = 4096;            // 1,048,576 threads -> ~64 iters/thread; stride % 8 == 0
    cwt_conv_kernel<<<grid, block, 0, stream>>>(x, kw, bias, out, total4, grid * block);
}